// Round 2
// baseline (952.044 us; speedup 1.0000x reference)
//
#include <hip/hip_runtime.h>
#include <math.h>

#define BB_ 32   // batch
#define PP_ 24   // sentences
#define SS_ 48   // tokens
#define HH_ 512  // hidden
#define FF_ 64   // feature
#define DD_ 576  // H+F
#define G4_ 2048 // 4H

__device__ __forceinline__ float sigf(float x) { return 1.f / (1.f + expf(-x)); }

// K0: detect x_mask dtype by content. Reads first 36864 bytes (size of the
// uint8 interpretation -> always in-bounds). int32 bool -> words in {0,1};
// uint8 bool -> masked runs give words with bytes 0/1 -> value > 1;
// float32 -> 0x3F800000 appears. mode: 0=int32, 1=uint8, 2=float32.
__global__ void detect_mask_kernel(const unsigned int* __restrict__ m,
                                   int* __restrict__ mode)
{
    __shared__ int s_u8, s_f32;
    int tid = threadIdx.x;
    if (tid == 0) { s_u8 = 0; s_f32 = 0; }
    __syncthreads();
    int u8 = 0, f32 = 0;
    for (int i = tid; i < 9216; i += 256) {
        unsigned int w = m[i];
        if (w == 0x3F800000u) f32 = 1;
        else if (w > 1u) u8 = 1;
    }
    if (u8) s_u8 = 1;      // racing writes of constant 1: fine
    if (f32) s_f32 = 1;
    __syncthreads();
    if (tid == 0) *mode = s_f32 ? 2 : (s_u8 ? 1 : 0);
}

// K1: attention + weighted pooling -> seq [P][B][D]
__global__ void attn_rep_kernel(const int* __restrict__ x,
                                const void* __restrict__ x_mask,
                                const int* __restrict__ mode_p,
                                const float* __restrict__ x_feature,
                                const float* __restrict__ emb,
                                const float* __restrict__ w_attn,
                                const float* __restrict__ b_attn,
                                float* __restrict__ seq)
{
    int bp = blockIdx.x;              // b*P + p
    int b = bp / PP_, p = bp % PP_;
    int tid = threadIdx.x;            // 256
    __shared__ float wattn_s[HH_];
    __shared__ float sc_s[SS_];
    __shared__ float alpha_s[SS_];
    __shared__ int idx_s[SS_];
    __shared__ unsigned char msk_s[SS_];
    int mode = *mode_p;               // uniform scalar load
    wattn_s[tid] = w_attn[tid];
    wattn_s[tid + 256] = w_attn[tid + 256];
    if (tid < SS_) {
        size_t i = (size_t)bp * SS_ + tid;
        idx_s[tid] = x[i];
        unsigned char mv;
        if (mode == 1)      mv = ((const unsigned char*)x_mask)[i];
        else if (mode == 2) mv = (((const float*)x_mask)[i] != 0.f);
        else                mv = (((const int*)x_mask)[i] != 0);
        msk_s[tid] = mv;
    }
    __syncthreads();
    int wave = tid >> 6, lane = tid & 63;
    for (int s = wave; s < SS_; s += 4) {
        const float* er = emb + (size_t)idx_s[s] * HH_;
        float acc = 0.f;
        #pragma unroll
        for (int j = 0; j < 8; ++j) {
            int d = lane * 8 + j;
            acc += er[d] * wattn_s[d];
        }
        #pragma unroll
        for (int off = 32; off > 0; off >>= 1) acc += __shfl_down(acc, off, 64);
        if (lane == 0) sc_s[s] = acc + b_attn[0];
    }
    __syncthreads();
    if (tid == 0) {
        float m = -3.4e38f;
        for (int s = 0; s < SS_; ++s) if (!msk_s[s] && sc_s[s] > m) m = sc_s[s];
        float sum = 0.f;
        for (int s = 0; s < SS_; ++s) {
            float a = 0.f;
            if (!msk_s[s]) { a = expf(sc_s[s] - m); sum += a; }
            alpha_s[s] = a;
        }
        float inv = (sum > 0.f) ? (1.f / sum) : 0.f;
        for (int s = 0; s < SS_; ++s) alpha_s[s] *= inv;
    }
    __syncthreads();
    float acc0 = 0.f, acc1 = 0.f;
    for (int s = 0; s < SS_; ++s) {
        float a = alpha_s[s];
        if (a != 0.f) {   // wave-uniform branch (a is an LDS broadcast scalar)
            const float* er = emb + (size_t)idx_s[s] * HH_;
            acc0 += a * er[tid];
            acc1 += a * er[tid + 256];
        }
    }
    float* orow = seq + ((size_t)p * BB_ + b) * DD_;
    orow[tid] = acc0;
    orow[tid + 256] = acc1;
    if (tid < FF_) {
        float acc2 = 0.f;
        for (int s = 0; s < SS_; ++s)
            if (!msk_s[s]) acc2 += x_feature[((size_t)bp * SS_ + s) * FF_ + tid];
        orow[HH_ + tid] = acc2;
    }
}

// zero h0 and c (ws is poisoned 0xAA before every call)
__global__ void init_kernel(float* __restrict__ h0, float* __restrict__ c)
{
    int idx = blockIdx.x * 256 + threadIdx.x;  // grid 64 -> 16384 = B*H
    h0[idx] = 0.f;
    c[idx] = 0.f;
}

// K3: forward input gates: Ain[p*B+b][n] = seq row . Wih_f[n][:] + bih+bhh
// NT SGEMM: M=768, N=2048, K=576, 64x64 tiles, 4x4 per thread
__global__ void in_gates_kernel(const float* __restrict__ A,     // [768][576]
                                const float* __restrict__ W,     // [2048][576]
                                const float* __restrict__ bih,
                                const float* __restrict__ bhh,
                                float* __restrict__ Cout)        // [768][2048]
{
    __shared__ float As[16][65];
    __shared__ float Bs[16][65];
    int tid = threadIdx.x;
    int n0 = blockIdx.x * 64;   // 32 tiles
    int m0 = blockIdx.y * 64;   // 12 tiles
    int tx = tid & 15, ty = tid >> 4;
    int lm = tid >> 2;          // 0..63
    int lk = (tid & 3) << 2;    // 0,4,8,12
    float acc[4][4] = {};
    for (int k0 = 0; k0 < DD_; k0 += 16) {
        float4 av = *(const float4*)(A + (size_t)(m0 + lm) * DD_ + k0 + lk);
        float4 bv = *(const float4*)(W + (size_t)(n0 + lm) * DD_ + k0 + lk);
        As[lk + 0][lm] = av.x; As[lk + 1][lm] = av.y; As[lk + 2][lm] = av.z; As[lk + 3][lm] = av.w;
        Bs[lk + 0][lm] = bv.x; Bs[lk + 1][lm] = bv.y; Bs[lk + 2][lm] = bv.z; Bs[lk + 3][lm] = bv.w;
        __syncthreads();
        #pragma unroll
        for (int kk = 0; kk < 16; ++kk) {
            float a0[4], b0[4];
            #pragma unroll
            for (int i = 0; i < 4; ++i) a0[i] = As[kk][ty * 4 + i];
            #pragma unroll
            for (int j = 0; j < 4; ++j) b0[j] = Bs[kk][tx * 4 + j];
            #pragma unroll
            for (int i = 0; i < 4; ++i)
                #pragma unroll
                for (int j = 0; j < 4; ++j) acc[i][j] += a0[i] * b0[j];
        }
        __syncthreads();
    }
    #pragma unroll
    for (int i = 0; i < 4; ++i) {
        int m = m0 + ty * 4 + i;
        #pragma unroll
        for (int j = 0; j < 4; ++j) {
            int n = n0 + tx * 4 + j;
            Cout[(size_t)m * G4_ + n] = acc[i][j] + bih[n] + bhh[n];
        }
    }
}

// K2: backward LSTM collapses to one step from zero state on seq[lens[b]-1, b]
__global__ void bwd_last_kernel(const float* __restrict__ seq,
                                const int* __restrict__ lens,
                                const float* __restrict__ Wih_b,
                                const float* __restrict__ bih_b,
                                const float* __restrict__ bhh_b,
                                float* __restrict__ hb)   // [B][H]
{
    int b = blockIdx.x;
    int tid = threadIdx.x;  // 256
    __shared__ float xs[DD_];
    int j = lens[b] - 1;
    const float* xr = seq + ((size_t)j * BB_ + b) * DD_;
    for (int d = tid; d < DD_; d += 256) xs[d] = xr[d];
    __syncthreads();
    for (int u = tid; u < HH_; u += 256) {
        const float* wi = Wih_b + (size_t)u * DD_;
        const float* wg = Wih_b + (size_t)(2 * HH_ + u) * DD_;
        const float* wo = Wih_b + (size_t)(3 * HH_ + u) * DD_;
        float gi = 0.f, gg = 0.f, go = 0.f;
        for (int k = 0; k < DD_; k += 4) {
            float4 a = *(const float4*)(wi + k);
            float4 c = *(const float4*)(wg + k);
            float4 d4 = *(const float4*)(wo + k);
            float x0 = xs[k], x1 = xs[k + 1], x2 = xs[k + 2], x3 = xs[k + 3];
            gi += a.x * x0 + a.y * x1 + a.z * x2 + a.w * x3;
            gg += c.x * x0 + c.y * x1 + c.z * x2 + c.w * x3;
            go += d4.x * x0 + d4.y * x1 + d4.z * x2 + d4.w * x3;
        }
        gi += bih_b[u] + bhh_b[u];
        gg += bih_b[2 * HH_ + u] + bhh_b[2 * HH_ + u];
        go += bih_b[3 * HH_ + u] + bhh_b[3 * HH_ + u];
        float cc = sigf(gi) * tanhf(gg);        // c0 = 0 -> forget term vanishes
        hb[(size_t)b * HH_ + u] = sigf(go) * tanhf(cc);
    }
}

// K4: one forward LSTM step. 128 blocks x 256 thr: block = 4 hidden units x all 32 batches.
// h staged in LDS [k][b] with XOR swizzle -> conflict-free stage AND read; exactly 64 KB.
__global__ void __launch_bounds__(256) lstm_step_kernel(const float* __restrict__ hsrc,
        float* __restrict__ hdst, float* __restrict__ cbuf,
        const float* __restrict__ AinT,   // [B][2048] for this t
        const float* __restrict__ Whh)
{
    __shared__ float hs[16384];
    int tid = threadIdx.x;
    for (int q = tid; q < 16384; q += 256) {
        int bb = q >> 9, k = q & 511;
        hs[(k << 5) + ((bb ^ k) & 31)] = hsrc[q];
    }
    __syncthreads();
    int u = tid >> 6;           // 0..3
    int gp = (tid >> 5) & 1;    // gate pair: 0 -> {i,f}, 1 -> {g,o}
    int b = tid & 31;
    int ug = blockIdx.x * 4 + u;
    int ga0 = gp * 2, ga1 = gp * 2 + 1;
    const float* w0 = Whh + (size_t)(ga0 * HH_ + ug) * HH_;
    const float* w1 = Whh + (size_t)(ga1 * HH_ + ug) * HH_;
    float a0 = 0.f, a1 = 0.f;
    #pragma unroll 8
    for (int k = 0; k < HH_; k += 4) {
        float4 wv0 = *(const float4*)(w0 + k);   // broadcast across the 32 b-lanes
        float4 wv1 = *(const float4*)(w1 + k);
        float h0v = hs[((k + 0) << 5) + ((b ^ (k + 0)) & 31)];
        float h1v = hs[((k + 1) << 5) + ((b ^ (k + 1)) & 31)];
        float h2v = hs[((k + 2) << 5) + ((b ^ (k + 2)) & 31)];
        float h3v = hs[((k + 3) << 5) + ((b ^ (k + 3)) & 31)];
        a0 += wv0.x * h0v + wv0.y * h1v + wv0.z * h2v + wv0.w * h3v;
        a1 += wv1.x * h0v + wv1.y * h1v + wv1.z * h2v + wv1.w * h3v;
    }
    a0 += AinT[(size_t)b * G4_ + ga0 * HH_ + ug];
    a1 += AinT[(size_t)b * G4_ + ga1 * HH_ + ug];
    float v0 = (gp == 1) ? tanhf(a0) : sigf(a0);  // gate 2 (g) is tanh; 0 (i) sigmoid
    float v1 = sigf(a1);                          // gates 1 (f), 3 (o) sigmoid
    __syncthreads();                              // everyone done reading hs
    hs[((u * 4 + ga0) << 5) + b] = v0;            // reuse first 2 KB of hs for gates
    hs[((u * 4 + ga1) << 5) + b] = v1;
    __syncthreads();
    if (tid < 128) {
        int uu = tid >> 5, bb2 = tid & 31;
        int ugg = blockIdx.x * 4 + uu;
        float iv = hs[((uu * 4 + 0) << 5) + bb2];
        float fv = hs[((uu * 4 + 1) << 5) + bb2];
        float gv = hs[((uu * 4 + 2) << 5) + bb2];
        float ov = hs[((uu * 4 + 3) << 5) + bb2];
        float cold = cbuf[(size_t)bb2 * HH_ + ugg];
        float cn = fv * cold + iv * gv;
        cbuf[(size_t)bb2 * HH_ + ugg] = cn;
        hdst[(size_t)bb2 * HH_ + ugg] = ov * tanhf(cn);
    }
}

// K5: head. last[b] = [hf[b], hb[b]] * (lens[b]==P). z[i,j] = last[j%32][i*32+j/32].
// y = z@Wfc.T + bfc; layernorm over batch axis; relu; log_softmax over batch axis.
__global__ void __launch_bounds__(512) head_kernel(const float* __restrict__ hf,
        const float* __restrict__ hb, const int* __restrict__ lens,
        const float* __restrict__ Wfc, const float* __restrict__ bfc,
        const float* __restrict__ gamma, const float* __restrict__ beta,
        float* __restrict__ out)
{
    int tid = threadIdx.x;  // 512; i = tid>>4, o = tid&15 (o lane-fast -> coalesced out)
    __shared__ float msk[BB_];
    __shared__ float ys[16][33];
    __shared__ float cstat[16];
    if (tid < BB_) msk[tid] = (lens[tid] == PP_) ? 1.f : 0.f;
    __syncthreads();
    int i = tid >> 4, o = tid & 15;
    float acc = bfc[o];
    const float* w = Wfc + (size_t)o * 1024;
    for (int jq = 0; jq < 32; ++jq) {
        int col = i * 32 + jq;                  // j/32
        const float* src = (col < HH_) ? (hf + col) : (hb + col - HH_);
        const float* wp = w + jq * 32;
        #pragma unroll
        for (int bb = 0; bb < 32; ++bb)         // bb = j%32
            acc += wp[bb] * src[(size_t)bb * HH_] * msk[bb];
    }
    ys[o][i] = acc;
    __syncthreads();
    if (tid < 16) {
        float mean = 0.f;
        for (int ii = 0; ii < 32; ++ii) mean += ys[tid][ii];
        mean *= (1.f / 32.f);
        float var = 0.f;
        for (int ii = 0; ii < 32; ++ii) { float d = ys[tid][ii] - mean; var += d * d; }
        var *= (1.f / 32.f);
        float inv = 1.f / sqrtf(var + 1e-5f);
        float g = gamma[tid], bt = beta[tid];
        float mx = -3.4e38f;
        for (int ii = 0; ii < 32; ++ii) {
            float v = g * (ys[tid][ii] - mean) * inv + bt;
            v = fmaxf(v, 0.f);
            ys[tid][ii] = v;
            mx = fmaxf(mx, v);
        }
        float s = 0.f;
        for (int ii = 0; ii < 32; ++ii) s += expf(ys[tid][ii] - mx);
        cstat[tid] = mx + logf(s);
    }
    __syncthreads();
    out[tid] = ys[o][i] - cstat[o];   // out[i*16+o]
}

extern "C" void kernel_launch(void* const* d_in, const int* in_sizes, int n_in,
                              void* d_out, int out_size, void* d_ws, size_t ws_size,
                              hipStream_t stream) {
    const int* x            = (const int*)d_in[0];
    const void* xm          = d_in[1];           // bool mask: dtype detected on device
    const float* x_feature  = (const float*)d_in[2];
    const int* lens         = (const int*)d_in[3];
    // d_in[4]=clause, d_in[5]=cls unused
    const float* emb    = (const float*)d_in[6];
    const float* w_attn = (const float*)d_in[7];
    const float* b_attn = (const float*)d_in[8];
    const float* Wih_f  = (const float*)d_in[9];
    const float* Whh_f  = (const float*)d_in[10];
    const float* bih_f  = (const float*)d_in[11];
    const float* bhh_f  = (const float*)d_in[12];
    const float* Wih_b  = (const float*)d_in[13];
    // d_in[14] = Whh_b unused (backward LSTM collapses to step 1 from zero state)
    const float* bih_b  = (const float*)d_in[15];
    const float* bhh_b  = (const float*)d_in[16];
    const float* Wfc    = (const float*)d_in[17];
    const float* bfc    = (const float*)d_in[18];
    const float* gamma  = (const float*)d_in[19];
    const float* beta   = (const float*)d_in[20];

    float* ws   = (float*)d_ws;
    float* seq  = ws;                                  // P*B*D   = 442368
    float* Ain  = seq + (size_t)PP_ * BB_ * DD_;       // P*B*4H  = 1572864
    float* hb   = Ain + (size_t)PP_ * BB_ * G4_;       // B*H
    float* h0   = hb + (size_t)BB_ * HH_;              // B*H
    float* h1   = h0 + (size_t)BB_ * HH_;              // B*H
    float* cbuf = h1 + (size_t)BB_ * HH_;              // B*H
    int*  mflag = (int*)(cbuf + (size_t)BB_ * HH_);    // 1 int (total ~8.3 MB)

    float* outp = (float*)d_out;

    detect_mask_kernel<<<dim3(1), dim3(256), 0, stream>>>(
        (const unsigned int*)xm, mflag);
    attn_rep_kernel<<<dim3(BB_ * PP_), dim3(256), 0, stream>>>(
        x, xm, mflag, x_feature, emb, w_attn, b_attn, seq);
    init_kernel<<<dim3(64), dim3(256), 0, stream>>>(h0, cbuf);
    in_gates_kernel<<<dim3(32, 12), dim3(256), 0, stream>>>(
        seq, Wih_f, bih_f, bhh_f, Ain);
    bwd_last_kernel<<<dim3(BB_), dim3(256), 0, stream>>>(
        seq, lens, Wih_b, bih_b, bhh_b, hb);
    for (int t = 0; t < PP_; ++t) {
        const float* hsrc = (t & 1) ? h1 : h0;
        float* hdst       = (t & 1) ? h0 : h1;
        lstm_step_kernel<<<dim3(128), dim3(256), 0, stream>>>(
            hsrc, hdst, cbuf, Ain + (size_t)t * BB_ * G4_, Whh_f);
    }
    // P=24 even -> final forward h lives in h0
    head_kernel<<<dim3(1), dim3(512), 0, stream>>>(
        h0, hb, lens, Wfc, bfc, gamma, beta, outp);
}

// Round 3
// 543.502 us; speedup vs baseline: 1.7517x; 1.7517x over previous
//
#include <hip/hip_runtime.h>
#include <math.h>

#define BB_ 32   // batch
#define PP_ 24   // sentences
#define SS_ 48   // tokens
#define HH_ 512  // hidden
#define FF_ 64   // feature
#define DD_ 576  // H+F
#define G4_ 2048 // 4H

typedef __attribute__((ext_vector_type(8))) short short8;
typedef __attribute__((ext_vector_type(4))) float f32x4;

__device__ __forceinline__ float sigf(float x) { return 1.f / (1.f + expf(-x)); }

__device__ __forceinline__ unsigned short f2bf(float f) {
    unsigned int u = __float_as_uint(f);
    u += 0x7FFFu + ((u >> 16) & 1u);     // RNE
    return (unsigned short)(u >> 16);
}

// K0: detect x_mask dtype by content (int32 / uint8 / float32 bool).
__global__ void detect_mask_kernel(const unsigned int* __restrict__ m,
                                   int* __restrict__ mode)
{
    __shared__ int s_u8, s_f32;
    int tid = threadIdx.x;
    if (tid == 0) { s_u8 = 0; s_f32 = 0; }
    __syncthreads();
    int u8 = 0, f32 = 0;
    for (int i = tid; i < 9216; i += 256) {
        unsigned int w = m[i];
        if (w == 0x3F800000u) f32 = 1;
        else if (w > 1u) u8 = 1;
    }
    if (u8) s_u8 = 1;
    if (f32) s_f32 = 1;
    __syncthreads();
    if (tid == 0) *mode = s_f32 ? 2 : (s_u8 ? 1 : 0);
}

// K1: attention + weighted pooling -> seq [P][B][D]
__global__ void attn_rep_kernel(const int* __restrict__ x,
                                const void* __restrict__ x_mask,
                                const int* __restrict__ mode_p,
                                const float* __restrict__ x_feature,
                                const float* __restrict__ emb,
                                const float* __restrict__ w_attn,
                                const float* __restrict__ b_attn,
                                float* __restrict__ seq)
{
    int bp = blockIdx.x;              // b*P + p
    int b = bp / PP_, p = bp % PP_;
    int tid = threadIdx.x;            // 256
    __shared__ float wattn_s[HH_];
    __shared__ float sc_s[SS_];
    __shared__ float alpha_s[SS_];
    __shared__ int idx_s[SS_];
    __shared__ unsigned char msk_s[SS_];
    int mode = *mode_p;
    wattn_s[tid] = w_attn[tid];
    wattn_s[tid + 256] = w_attn[tid + 256];
    if (tid < SS_) {
        size_t i = (size_t)bp * SS_ + tid;
        idx_s[tid] = x[i];
        unsigned char mv;
        if (mode == 1)      mv = ((const unsigned char*)x_mask)[i];
        else if (mode == 2) mv = (((const float*)x_mask)[i] != 0.f);
        else                mv = (((const int*)x_mask)[i] != 0);
        msk_s[tid] = mv;
    }
    __syncthreads();
    int wave = tid >> 6, lane = tid & 63;
    for (int s = wave; s < SS_; s += 4) {
        const float* er = emb + (size_t)idx_s[s] * HH_;
        float acc = 0.f;
        #pragma unroll
        for (int j = 0; j < 8; ++j) {
            int d = lane * 8 + j;
            acc += er[d] * wattn_s[d];
        }
        #pragma unroll
        for (int off = 32; off > 0; off >>= 1) acc += __shfl_down(acc, off, 64);
        if (lane == 0) sc_s[s] = acc + b_attn[0];
    }
    __syncthreads();
    if (tid == 0) {
        float m = -3.4e38f;
        for (int s = 0; s < SS_; ++s) if (!msk_s[s] && sc_s[s] > m) m = sc_s[s];
        float sum = 0.f;
        for (int s = 0; s < SS_; ++s) {
            float a = 0.f;
            if (!msk_s[s]) { a = expf(sc_s[s] - m); sum += a; }
            alpha_s[s] = a;
        }
        float inv = (sum > 0.f) ? (1.f / sum) : 0.f;
        for (int s = 0; s < SS_; ++s) alpha_s[s] *= inv;
    }
    __syncthreads();
    float acc0 = 0.f, acc1 = 0.f;
    for (int s = 0; s < SS_; ++s) {
        float a = alpha_s[s];
        if (a != 0.f) {
            const float* er = emb + (size_t)idx_s[s] * HH_;
            acc0 += a * er[tid];
            acc1 += a * er[tid + 256];
        }
    }
    float* orow = seq + ((size_t)p * BB_ + b) * DD_;
    orow[tid] = acc0;
    orow[tid + 256] = acc1;
    if (tid < FF_) {
        float acc2 = 0.f;
        for (int s = 0; s < SS_; ++s)
            if (!msk_s[s]) acc2 += x_feature[((size_t)bp * SS_ + s) * FF_ + tid];
        orow[HH_ + tid] = acc2;
    }
}

// zero A-frag buffer 0 (h0 = 0, 16384 bf16 = 8192 floats) and cbuf (16384 floats)
__global__ void init2_kernel(float* __restrict__ A0, float* __restrict__ cb)
{
    int i = blockIdx.x * 256 + threadIdx.x;   // grid 64 -> 16384
    if (i < 8192) A0[i] = 0.f;
    cb[i] = 0.f;
}

// K3: forward input gates: Ain[p*B+b][n] = seq row . Wih_f[n][:] + bih+bhh
__global__ void in_gates_kernel(const float* __restrict__ A,     // [768][576]
                                const float* __restrict__ W,     // [2048][576]
                                const float* __restrict__ bih,
                                const float* __restrict__ bhh,
                                float* __restrict__ Cout)        // [768][2048]
{
    __shared__ float As[16][65];
    __shared__ float Bs[16][65];
    int tid = threadIdx.x;
    int n0 = blockIdx.x * 64;
    int m0 = blockIdx.y * 64;
    int tx = tid & 15, ty = tid >> 4;
    int lm = tid >> 2;
    int lk = (tid & 3) << 2;
    float acc[4][4] = {};
    for (int k0 = 0; k0 < DD_; k0 += 16) {
        float4 av = *(const float4*)(A + (size_t)(m0 + lm) * DD_ + k0 + lk);
        float4 bv = *(const float4*)(W + (size_t)(n0 + lm) * DD_ + k0 + lk);
        As[lk + 0][lm] = av.x; As[lk + 1][lm] = av.y; As[lk + 2][lm] = av.z; As[lk + 3][lm] = av.w;
        Bs[lk + 0][lm] = bv.x; Bs[lk + 1][lm] = bv.y; Bs[lk + 2][lm] = bv.z; Bs[lk + 3][lm] = bv.w;
        __syncthreads();
        #pragma unroll
        for (int kk = 0; kk < 16; ++kk) {
            float a0[4], b0[4];
            #pragma unroll
            for (int i = 0; i < 4; ++i) a0[i] = As[kk][ty * 4 + i];
            #pragma unroll
            for (int j = 0; j < 4; ++j) b0[j] = Bs[kk][tx * 4 + j];
            #pragma unroll
            for (int i = 0; i < 4; ++i)
                #pragma unroll
                for (int j = 0; j < 4; ++j) acc[i][j] += a0[i] * b0[j];
        }
        __syncthreads();
    }
    #pragma unroll
    for (int i = 0; i < 4; ++i) {
        int m = m0 + ty * 4 + i;
        #pragma unroll
        for (int j = 0; j < 4; ++j) {
            int n = n0 + tx * 4 + j;
            Cout[(size_t)m * G4_ + n] = acc[i][j] + bih[n] + bhh[n];
        }
    }
}

// K2 v2: backward LSTM one step. 64 blocks x 256 thr = 8 units x 32 batches.
// All 32 gathered x-vectors staged in LDS [k][b] (+1 pad word per k row via *33).
__global__ void __launch_bounds__(256) bwd_last2_kernel(const float* __restrict__ seq,
        const int* __restrict__ lens,
        const float* __restrict__ Wih_b,
        const float* __restrict__ bih_b,
        const float* __restrict__ bhh_b,
        float* __restrict__ hb)   // [B][H]
{
    __shared__ float xsT[DD_ * 33];   // 74.25 KB
    __shared__ int pl[BB_];
    int tid = threadIdx.x;
    if (tid < BB_) pl[tid] = lens[tid] - 1;
    __syncthreads();
    for (int idx = tid; idx < BB_ * DD_; idx += 256) {
        int b2 = idx / DD_;
        int k = idx - b2 * DD_;
        xsT[k * 33 + b2] = seq[((size_t)pl[b2] * BB_ + b2) * DD_ + k];
    }
    __syncthreads();
    int b = tid & 31, ul = tid >> 5;
    int u = blockIdx.x * 8 + ul;
    const float* wi = Wih_b + (size_t)u * DD_;                 // gate i
    const float* wg = Wih_b + (size_t)(2 * HH_ + u) * DD_;     // gate g
    const float* wo = Wih_b + (size_t)(3 * HH_ + u) * DD_;     // gate o
    float gi = 0.f, gg = 0.f, go = 0.f;
    #pragma unroll 4
    for (int k = 0; k < DD_; k += 4) {
        float4 w1 = *(const float4*)(wi + k);   // wave-broadcast (2 addrs/wave)
        float4 w2 = *(const float4*)(wg + k);
        float4 w3 = *(const float4*)(wo + k);
        float x0 = xsT[(k + 0) * 33 + b];
        float x1 = xsT[(k + 1) * 33 + b];
        float x2 = xsT[(k + 2) * 33 + b];
        float x3 = xsT[(k + 3) * 33 + b];
        gi += w1.x * x0 + w1.y * x1 + w1.z * x2 + w1.w * x3;
        gg += w2.x * x0 + w2.y * x1 + w2.z * x2 + w2.w * x3;
        go += w3.x * x0 + w3.y * x1 + w3.z * x2 + w3.w * x3;
    }
    gi += bih_b[u] + bhh_b[u];
    gg += bih_b[2 * HH_ + u] + bhh_b[2 * HH_ + u];
    go += bih_b[3 * HH_ + u] + bhh_b[3 * HH_ + u];
    float cc = sigf(gi) * tanhf(gg);   // c0 = 0
    hb[(size_t)b * HH_ + u] = sigf(go) * tanhf(cc);
}

// K5: convert Whh_f fp32 [2048][512] -> bf16 B-fragment order, once per launch.
// Bf flat index ((nb*2+ti)*16+ks)*64+lane holds 8 bf16: Whh[row][ks*32+q*8+j]
// with row = (ti*2 + (c>>3))*512 + nb*8 + (c&7), c=lane&15, q=lane>>4.
__global__ void whh_frag_kernel(const float* __restrict__ Whh,
                                unsigned short* __restrict__ Bf)
{
    int idx = blockIdx.x * 256 + threadIdx.x;   // 131072 total
    int lane = idx & 63;
    int ks = (idx >> 6) & 15;
    int ti = (idx >> 10) & 1;
    int nb = idx >> 11;
    int c = lane & 15, q = lane >> 4;
    int nrow = (ti * 2 + (c >> 3)) * HH_ + nb * 8 + (c & 7);
    int k0 = ks * 32 + q * 8;
    const float* src = Whh + (size_t)nrow * HH_ + k0;
    unsigned int w0 = (unsigned int)f2bf(src[0]) | ((unsigned int)f2bf(src[1]) << 16);
    unsigned int w1 = (unsigned int)f2bf(src[2]) | ((unsigned int)f2bf(src[3]) << 16);
    unsigned int w2 = (unsigned int)f2bf(src[4]) | ((unsigned int)f2bf(src[5]) << 16);
    unsigned int w3 = (unsigned int)f2bf(src[6]) | ((unsigned int)f2bf(src[7]) << 16);
    uint4 v = make_uint4(w0, w1, w2, w3);
    *(uint4*)(Bf + (size_t)idx * 8) = v;       // coalesced 16B store
}

// K4 v2: one forward LSTM step via MFMA bf16. 64 blocks x 256 thr.
// Block nb owns hidden units [nb*8, nb*8+8) x 4 gates = 32 N-rows (2 N-tiles).
// Wave (mt,ti): M-tile mt (batches 16mt..), N-tile ti. 16 MFMAs over K=512.
// A (h) read/written in fragment order, double-buffered across steps.
__global__ void __launch_bounds__(256) lstm_mfma_kernel(
        const unsigned short* __restrict__ Afrag,   // 16384 bf16, frag order
        unsigned short* __restrict__ AfragN,        // next step's A
        float* __restrict__ cbuf,                   // [B][H]
        float* __restrict__ hbuf,                   // [B][H] fp32 h (for head)
        const float* __restrict__ Ain_t,            // [B][2048] this t
        const unsigned short* __restrict__ Bfrag)
{
    __shared__ float gl[32 * 33];    // gates [g*8+ul][b], +1 pad
    int tid = threadIdx.x;
    int lane = tid & 63;
    int wv = tid >> 6;
    int mt = wv & 1, ti = wv >> 1;
    int nb = blockIdx.x;
    const short8* Ap = (const short8*)Afrag + (size_t)(mt * 16) * 64 + lane;
    const short8* Bp = (const short8*)Bfrag + (((size_t)nb * 2 + ti) * 16) * 64 + lane;
    short8 a[16], bfr[16];
    #pragma unroll
    for (int ks = 0; ks < 16; ++ks) { a[ks] = Ap[ks * 64]; bfr[ks] = Bp[ks * 64]; }
    f32x4 acc = {0.f, 0.f, 0.f, 0.f};
    #pragma unroll
    for (int ks = 0; ks < 16; ++ks)
        acc = __builtin_amdgcn_mfma_f32_16x16x32_bf16(a[ks], bfr[ks], acc, 0, 0, 0);
    int c = lane & 15, q = lane >> 4;
    int g = ti * 2 + (c >> 3), ul = c & 7;
    #pragma unroll
    for (int r = 0; r < 4; ++r) {
        int bb = mt * 16 + q * 4 + r;                       // C/D: row=quad*4+reg
        float v = acc[r] + Ain_t[(size_t)bb * G4_ + g * HH_ + nb * 8 + ul];
        v = (g == 2) ? tanhf(v) : sigf(v);                  // gate order i,f,g,o
        gl[(g * 8 + ul) * 33 + bb] = v;
    }
    __syncthreads();
    int b2 = tid >> 3, u2 = tid & 7;
    float iv = gl[(0  + u2) * 33 + b2];
    float fv = gl[(8  + u2) * 33 + b2];
    float gv = gl[(16 + u2) * 33 + b2];
    float ov = gl[(24 + u2) * 33 + b2];
    int ug = nb * 8 + u2;
    size_t ci = (size_t)b2 * HH_ + ug;
    float cold = cbuf[ci];
    float cn = fv * cold + iv * gv;
    cbuf[ci] = cn;
    float h = ov * tanhf(cn);
    hbuf[ci] = h;
    // scatter h into next step's A-fragment layout
    int ks2 = ug >> 5, q2 = (ug >> 3) & 3, j2 = ug & 7;
    int lane2 = (b2 & 15) + 16 * q2;
    AfragN[(((size_t)(b2 >> 4) * 16 + ks2) * 64 + lane2) * 8 + j2] = f2bf(h);
}

// K6: head. last[b] = [hf[b], hb[b]] * (lens[b]==P). z[i,j] = last[j%32][i*32+j/32].
__global__ void __launch_bounds__(512) head_kernel(const float* __restrict__ hf,
        const float* __restrict__ hb, const int* __restrict__ lens,
        const float* __restrict__ Wfc, const float* __restrict__ bfc,
        const float* __restrict__ gamma, const float* __restrict__ beta,
        float* __restrict__ out)
{
    int tid = threadIdx.x;
    __shared__ float msk[BB_];
    __shared__ float ys[16][33];
    __shared__ float cstat[16];
    if (tid < BB_) msk[tid] = (lens[tid] == PP_) ? 1.f : 0.f;
    __syncthreads();
    int i = tid >> 4, o = tid & 15;
    float acc = bfc[o];
    const float* w = Wfc + (size_t)o * 1024;
    for (int jq = 0; jq < 32; ++jq) {
        int col = i * 32 + jq;
        const float* src = (col < HH_) ? (hf + col) : (hb + col - HH_);
        const float* wp = w + jq * 32;
        #pragma unroll
        for (int bb = 0; bb < 32; ++bb)
            acc += wp[bb] * src[(size_t)bb * HH_] * msk[bb];
    }
    ys[o][i] = acc;
    __syncthreads();
    if (tid < 16) {
        float mean = 0.f;
        for (int ii = 0; ii < 32; ++ii) mean += ys[tid][ii];
        mean *= (1.f / 32.f);
        float var = 0.f;
        for (int ii = 0; ii < 32; ++ii) { float d = ys[tid][ii] - mean; var += d * d; }
        var *= (1.f / 32.f);
        float inv = 1.f / sqrtf(var + 1e-5f);
        float g = gamma[tid], bt = beta[tid];
        float mx = -3.4e38f;
        for (int ii = 0; ii < 32; ++ii) {
            float v = g * (ys[tid][ii] - mean) * inv + bt;
            v = fmaxf(v, 0.f);
            ys[tid][ii] = v;
            mx = fmaxf(mx, v);
        }
        float s = 0.f;
        for (int ii = 0; ii < 32; ++ii) s += expf(ys[tid][ii] - mx);
        cstat[tid] = mx + logf(s);
    }
    __syncthreads();
    out[tid] = ys[o][i] - cstat[o];
}

extern "C" void kernel_launch(void* const* d_in, const int* in_sizes, int n_in,
                              void* d_out, int out_size, void* d_ws, size_t ws_size,
                              hipStream_t stream) {
    const int* x            = (const int*)d_in[0];
    const void* xm          = d_in[1];
    const float* x_feature  = (const float*)d_in[2];
    const int* lens         = (const int*)d_in[3];
    const float* emb    = (const float*)d_in[6];
    const float* w_attn = (const float*)d_in[7];
    const float* b_attn = (const float*)d_in[8];
    const float* Wih_f  = (const float*)d_in[9];
    const float* Whh_f  = (const float*)d_in[10];
    const float* bih_f  = (const float*)d_in[11];
    const float* bhh_f  = (const float*)d_in[12];
    const float* Wih_b  = (const float*)d_in[13];
    const float* bih_b  = (const float*)d_in[15];
    const float* bhh_b  = (const float*)d_in[16];
    const float* Wfc    = (const float*)d_in[17];
    const float* bfc    = (const float*)d_in[18];
    const float* gamma  = (const float*)d_in[19];
    const float* beta   = (const float*)d_in[20];

    float* ws    = (float*)d_ws;
    float* seq   = ws;                                    // 442368
    float* Ain   = seq + (size_t)PP_ * BB_ * DD_;         // 1572864
    float* hb    = Ain + (size_t)PP_ * BB_ * G4_;         // 16384
    float* hbuf  = hb + (size_t)BB_ * HH_;                // 16384
    float* cbuf  = hbuf + (size_t)BB_ * HH_;              // 16384
    float* AfA   = cbuf + (size_t)BB_ * HH_;              // 8192 (16384 bf16)
    float* AfB   = AfA + 8192;                            // 8192
    float* Bfrag = AfB + 8192;                            // 524288 (1M bf16)
    int*  mflag  = (int*)(Bfrag + 524288);                // 1  (~10.4 MB total)

    float* outp = (float*)d_out;

    detect_mask_kernel<<<dim3(1), dim3(256), 0, stream>>>(
        (const unsigned int*)xm, mflag);
    whh_frag_kernel<<<dim3(512), dim3(256), 0, stream>>>(
        Whh_f, (unsigned short*)Bfrag);
    attn_rep_kernel<<<dim3(BB_ * PP_), dim3(256), 0, stream>>>(
        x, xm, mflag, x_feature, emb, w_attn, b_attn, seq);
    init2_kernel<<<dim3(64), dim3(256), 0, stream>>>(AfA, cbuf);
    in_gates_kernel<<<dim3(32, 12), dim3(256), 0, stream>>>(
        seq, Wih_f, bih_f, bhh_f, Ain);
    bwd_last2_kernel<<<dim3(64), dim3(256), 0, stream>>>(
        seq, lens, Wih_b, bih_b, bhh_b, hb);
    for (int t = 0; t < PP_; ++t) {
        const unsigned short* Asrc = (const unsigned short*)((t & 1) ? AfB : AfA);
        unsigned short* Adst       = (unsigned short*)((t & 1) ? AfA : AfB);
        lstm_mfma_kernel<<<dim3(64), dim3(256), 0, stream>>>(
            Asrc, Adst, cbuf, hbuf, Ain + (size_t)t * BB_ * G4_,
            (const unsigned short*)Bfrag);
    }
    head_kernel<<<dim3(1), dim3(512), 0, stream>>>(
        hbuf, hb, lens, Wfc, bfc, gamma, beta, outp);
}

// Round 4
// 457.703 us; speedup vs baseline: 2.0800x; 1.1875x over previous
//
#include <hip/hip_runtime.h>
#include <math.h>

#define BB_ 32   // batch
#define PP_ 24   // sentences
#define SS_ 48   // tokens
#define HH_ 512  // hidden
#define FF_ 64   // feature
#define DD_ 576  // H+F
#define G4_ 2048 // 4H

typedef __attribute__((ext_vector_type(8))) short short8;
typedef __attribute__((ext_vector_type(4))) float f32x4;

__device__ __forceinline__ float sigf(float x) { return 1.f / (1.f + expf(-x)); }

__device__ __forceinline__ unsigned short f2bf(float f) {
    unsigned int u = __float_as_uint(f);
    u += 0x7FFFu + ((u >> 16) & 1u);     // RNE
    return (unsigned short)(u >> 16);
}

// K0: detect x_mask dtype by content (int32 / uint8 / float32 bool).
__global__ void detect_mask_kernel(const unsigned int* __restrict__ m,
                                   int* __restrict__ mode)
{
    __shared__ int s_u8, s_f32;
    int tid = threadIdx.x;
    if (tid == 0) { s_u8 = 0; s_f32 = 0; }
    __syncthreads();
    int u8 = 0, f32 = 0;
    for (int i = tid; i < 9216; i += 256) {
        unsigned int w = m[i];
        if (w == 0x3F800000u) f32 = 1;
        else if (w > 1u) u8 = 1;
    }
    if (u8) s_u8 = 1;
    if (f32) s_f32 = 1;
    __syncthreads();
    if (tid == 0) *mode = s_f32 ? 2 : (s_u8 ? 1 : 0);
}

// K1: attention + weighted pooling -> seq [P][B][D]
__global__ void attn_rep_kernel(const int* __restrict__ x,
                                const void* __restrict__ x_mask,
                                const int* __restrict__ mode_p,
                                const float* __restrict__ x_feature,
                                const float* __restrict__ emb,
                                const float* __restrict__ w_attn,
                                const float* __restrict__ b_attn,
                                float* __restrict__ seq)
{
    int bp = blockIdx.x;              // b*P + p
    int b = bp / PP_, p = bp % PP_;
    int tid = threadIdx.x;            // 256
    __shared__ float wattn_s[HH_];
    __shared__ float sc_s[SS_];
    __shared__ float alpha_s[SS_];
    __shared__ int idx_s[SS_];
    __shared__ unsigned char msk_s[SS_];
    int mode = *mode_p;
    wattn_s[tid] = w_attn[tid];
    wattn_s[tid + 256] = w_attn[tid + 256];
    if (tid < SS_) {
        size_t i = (size_t)bp * SS_ + tid;
        idx_s[tid] = x[i];
        unsigned char mv;
        if (mode == 1)      mv = ((const unsigned char*)x_mask)[i];
        else if (mode == 2) mv = (((const float*)x_mask)[i] != 0.f);
        else                mv = (((const int*)x_mask)[i] != 0);
        msk_s[tid] = mv;
    }
    __syncthreads();
    int wave = tid >> 6, lane = tid & 63;
    for (int s = wave; s < SS_; s += 4) {
        const float* er = emb + (size_t)idx_s[s] * HH_;
        float acc = 0.f;
        #pragma unroll
        for (int j = 0; j < 8; ++j) {
            int d = lane * 8 + j;
            acc += er[d] * wattn_s[d];
        }
        #pragma unroll
        for (int off = 32; off > 0; off >>= 1) acc += __shfl_down(acc, off, 64);
        if (lane == 0) sc_s[s] = acc + b_attn[0];
    }
    __syncthreads();
    if (tid == 0) {
        float m = -3.4e38f;
        for (int s = 0; s < SS_; ++s) if (!msk_s[s] && sc_s[s] > m) m = sc_s[s];
        float sum = 0.f;
        for (int s = 0; s < SS_; ++s) {
            float a = 0.f;
            if (!msk_s[s]) { a = expf(sc_s[s] - m); sum += a; }
            alpha_s[s] = a;
        }
        float inv = (sum > 0.f) ? (1.f / sum) : 0.f;
        for (int s = 0; s < SS_; ++s) alpha_s[s] *= inv;
    }
    __syncthreads();
    float acc0 = 0.f, acc1 = 0.f;
    for (int s = 0; s < SS_; ++s) {
        float a = alpha_s[s];
        if (a != 0.f) {
            const float* er = emb + (size_t)idx_s[s] * HH_;
            acc0 += a * er[tid];
            acc1 += a * er[tid + 256];
        }
    }
    float* orow = seq + ((size_t)p * BB_ + b) * DD_;
    orow[tid] = acc0;
    orow[tid + 256] = acc1;
    if (tid < FF_) {
        float acc2 = 0.f;
        for (int s = 0; s < SS_; ++s)
            if (!msk_s[s]) acc2 += x_feature[((size_t)bp * SS_ + s) * FF_ + tid];
        orow[HH_ + tid] = acc2;
    }
}

// zero A-frag buffer 0 (h0 = 0) and cbuf
__global__ void init2_kernel(float* __restrict__ A0, float* __restrict__ cb)
{
    int i = blockIdx.x * 256 + threadIdx.x;   // grid 64 -> 16384
    if (i < 8192) A0[i] = 0.f;
    cb[i] = 0.f;
}

// generic fp32 -> bf16 convert (vectorized x4)
__global__ void cvt_bf16_kernel(const float* __restrict__ s,
                                unsigned short* __restrict__ d, int n4)
{
    int i = blockIdx.x * 256 + threadIdx.x;
    if (i >= n4) return;
    float4 v = ((const float4*)s)[i];
    ushort4 o;
    o.x = f2bf(v.x); o.y = f2bf(v.y); o.z = f2bf(v.z); o.w = f2bf(v.w);
    ((ushort4*)d)[i] = o;
}

// K3 v2: input-gate GEMM via MFMA bf16. C[768][2048] = seq[768][576] @ Wih^T.
// grid (16 n-groups, 48 m-tiles), 256 thr. Wave w: 32 N-cols (2 frags).
// A converted fp32->bf16 on the fly; B pre-converted bf16 row-major.
__global__ void __launch_bounds__(256) in_gates_mfma_kernel(
        const float* __restrict__ A,              // seq fp32 [768][576]
        const unsigned short* __restrict__ Wbf,   // [2048][576] bf16
        const float* __restrict__ bih,
        const float* __restrict__ bhh,
        float* __restrict__ Cout)                 // [768][2048]
{
    int tid = threadIdx.x, lane = tid & 63, w = tid >> 6;
    int m0 = blockIdx.y * 16;
    int nb = blockIdx.x * 128 + w * 32;
    int c = lane & 15, q = lane >> 4;
    const float* Ap = A + (size_t)(m0 + c) * DD_ + q * 8;
    const unsigned short* Bp0 = Wbf + (size_t)(nb + c) * DD_ + q * 8;
    const unsigned short* Bp1 = Bp0 + 16 * DD_;
    f32x4 acc0 = {0.f, 0.f, 0.f, 0.f}, acc1 = {0.f, 0.f, 0.f, 0.f};
    for (int k = 0; k < DD_; k += 32) {
        float4 alo = *(const float4*)(Ap + k);
        float4 ahi = *(const float4*)(Ap + k + 4);
        short8 a;
        a[0] = (short)f2bf(alo.x); a[1] = (short)f2bf(alo.y);
        a[2] = (short)f2bf(alo.z); a[3] = (short)f2bf(alo.w);
        a[4] = (short)f2bf(ahi.x); a[5] = (short)f2bf(ahi.y);
        a[6] = (short)f2bf(ahi.z); a[7] = (short)f2bf(ahi.w);
        short8 b0 = *(const short8*)(Bp0 + k);
        short8 b1 = *(const short8*)(Bp1 + k);
        acc0 = __builtin_amdgcn_mfma_f32_16x16x32_bf16(a, b0, acc0, 0, 0, 0);
        acc1 = __builtin_amdgcn_mfma_f32_16x16x32_bf16(a, b1, acc1, 0, 0, 0);
    }
    #pragma unroll
    for (int r = 0; r < 4; ++r) {
        int m = m0 + q * 4 + r;              // C/D: row = quad*4 + reg
        int n0 = nb + c, n1 = nb + 16 + c;   // col = lane&15
        Cout[(size_t)m * G4_ + n0] = acc0[r] + bih[n0] + bhh[n0];
        Cout[(size_t)m * G4_ + n1] = acc1[r] + bih[n1] + bhh[n1];
    }
}

// K2: backward LSTM one step. 64 blocks x 256 thr = 8 units x 32 batches.
__global__ void __launch_bounds__(256) bwd_last2_kernel(const float* __restrict__ seq,
        const int* __restrict__ lens,
        const float* __restrict__ Wih_b,
        const float* __restrict__ bih_b,
        const float* __restrict__ bhh_b,
        float* __restrict__ hb)   // [B][H]
{
    __shared__ float xsT[DD_ * 33];
    __shared__ int pl[BB_];
    int tid = threadIdx.x;
    if (tid < BB_) pl[tid] = lens[tid] - 1;
    __syncthreads();
    for (int idx = tid; idx < BB_ * DD_; idx += 256) {
        int b2 = idx / DD_;
        int k = idx - b2 * DD_;
        xsT[k * 33 + b2] = seq[((size_t)pl[b2] * BB_ + b2) * DD_ + k];
    }
    __syncthreads();
    int b = tid & 31, ul = tid >> 5;
    int u = blockIdx.x * 8 + ul;
    const float* wi = Wih_b + (size_t)u * DD_;
    const float* wg = Wih_b + (size_t)(2 * HH_ + u) * DD_;
    const float* wo = Wih_b + (size_t)(3 * HH_ + u) * DD_;
    float gi = 0.f, gg = 0.f, go = 0.f;
    #pragma unroll 4
    for (int k = 0; k < DD_; k += 4) {
        float4 w1 = *(const float4*)(wi + k);
        float4 w2 = *(const float4*)(wg + k);
        float4 w3 = *(const float4*)(wo + k);
        float x0 = xsT[(k + 0) * 33 + b];
        float x1 = xsT[(k + 1) * 33 + b];
        float x2 = xsT[(k + 2) * 33 + b];
        float x3 = xsT[(k + 3) * 33 + b];
        gi += w1.x * x0 + w1.y * x1 + w1.z * x2 + w1.w * x3;
        gg += w2.x * x0 + w2.y * x1 + w2.z * x2 + w2.w * x3;
        go += w3.x * x0 + w3.y * x1 + w3.z * x2 + w3.w * x3;
    }
    gi += bih_b[u] + bhh_b[u];
    gg += bih_b[2 * HH_ + u] + bhh_b[2 * HH_ + u];
    go += bih_b[3 * HH_ + u] + bhh_b[3 * HH_ + u];
    float cc = sigf(gi) * tanhf(gg);   // c0 = 0
    hb[(size_t)b * HH_ + u] = sigf(go) * tanhf(cc);
}

// K5: convert Whh_f fp32 [2048][512] -> bf16 B-fragment order (for lstm_mfma).
__global__ void whh_frag_kernel(const float* __restrict__ Whh,
                                unsigned short* __restrict__ Bf)
{
    int idx = blockIdx.x * 256 + threadIdx.x;   // 131072 total
    int lane = idx & 63;
    int ks = (idx >> 6) & 15;
    int ti = (idx >> 10) & 1;
    int nb = idx >> 11;
    int c = lane & 15, q = lane >> 4;
    int nrow = (ti * 2 + (c >> 3)) * HH_ + nb * 8 + (c & 7);
    int k0 = ks * 32 + q * 8;
    const float* src = Whh + (size_t)nrow * HH_ + k0;
    unsigned int w0 = (unsigned int)f2bf(src[0]) | ((unsigned int)f2bf(src[1]) << 16);
    unsigned int w1 = (unsigned int)f2bf(src[2]) | ((unsigned int)f2bf(src[3]) << 16);
    unsigned int w2 = (unsigned int)f2bf(src[4]) | ((unsigned int)f2bf(src[5]) << 16);
    unsigned int w3 = (unsigned int)f2bf(src[6]) | ((unsigned int)f2bf(src[7]) << 16);
    uint4 v = make_uint4(w0, w1, w2, w3);
    *(uint4*)(Bf + (size_t)idx * 8) = v;
}

// K4: one forward LSTM step via MFMA bf16. 64 blocks x 256 thr.
__global__ void __launch_bounds__(256) lstm_mfma_kernel(
        const unsigned short* __restrict__ Afrag,
        unsigned short* __restrict__ AfragN,
        float* __restrict__ cbuf,
        float* __restrict__ hbuf,
        const float* __restrict__ Ain_t,
        const unsigned short* __restrict__ Bfrag)
{
    __shared__ float gl[32 * 33];
    int tid = threadIdx.x;
    int lane = tid & 63;
    int wv = tid >> 6;
    int mt = wv & 1, ti = wv >> 1;
    int nb = blockIdx.x;
    const short8* Ap = (const short8*)Afrag + (size_t)(mt * 16) * 64 + lane;
    const short8* Bp = (const short8*)Bfrag + (((size_t)nb * 2 + ti) * 16) * 64 + lane;
    short8 a[16], bfr[16];
    #pragma unroll
    for (int ks = 0; ks < 16; ++ks) { a[ks] = Ap[ks * 64]; bfr[ks] = Bp[ks * 64]; }
    f32x4 acc = {0.f, 0.f, 0.f, 0.f};
    #pragma unroll
    for (int ks = 0; ks < 16; ++ks)
        acc = __builtin_amdgcn_mfma_f32_16x16x32_bf16(a[ks], bfr[ks], acc, 0, 0, 0);
    int c = lane & 15, q = lane >> 4;
    int g = ti * 2 + (c >> 3), ul = c & 7;
    #pragma unroll
    for (int r = 0; r < 4; ++r) {
        int bb = mt * 16 + q * 4 + r;
        float v = acc[r] + Ain_t[(size_t)bb * G4_ + g * HH_ + nb * 8 + ul];
        v = (g == 2) ? tanhf(v) : sigf(v);
        gl[(g * 8 + ul) * 33 + bb] = v;
    }
    __syncthreads();
    int b2 = tid >> 3, u2 = tid & 7;
    float iv = gl[(0  + u2) * 33 + b2];
    float fv = gl[(8  + u2) * 33 + b2];
    float gv = gl[(16 + u2) * 33 + b2];
    float ov = gl[(24 + u2) * 33 + b2];
    int ug = nb * 8 + u2;
    size_t ci = (size_t)b2 * HH_ + ug;
    float cold = cbuf[ci];
    float cn = fv * cold + iv * gv;
    cbuf[ci] = cn;
    float h = ov * tanhf(cn);
    hbuf[ci] = h;
    int ks2 = ug >> 5, q2 = (ug >> 3) & 3, j2 = ug & 7;
    int lane2 = (b2 & 15) + 16 * q2;
    AfragN[(((size_t)(b2 >> 4) * 16 + ks2) * 64 + lane2) * 8 + j2] = f2bf(h);
}

// K6a: FC head, parallel. Block i (32 blocks) computes y[i][0..15].
// y[i][o] = sum_{bb,q} last[bb][i*32+q]*msk[bb] * Wfc[o][q*32+bb] + bfc[o]
__global__ void __launch_bounds__(256) fc_head_kernel(const float* __restrict__ hfwd,
        const float* __restrict__ hbwd, const int* __restrict__ lens,
        const float* __restrict__ Wfc, const float* __restrict__ bfc,
        float* __restrict__ yws)
{
    __shared__ float tile[32][33];
    __shared__ float part[16][17];
    int i = blockIdx.x;
    int tid = threadIdx.x;
    const float* src = (i < 16 ? hfwd : hbwd) + (size_t)(i & 15) * 32;
    int bb = tid >> 5, q = tid & 31;
    #pragma unroll
    for (int h = 0; h < 4; ++h) {
        int bi = bb + h * 8;
        float v = src[(size_t)bi * HH_ + q];
        tile[bi][q] = (lens[bi] == PP_) ? v : 0.f;
    }
    __syncthreads();
    int o = tid >> 4, s = tid & 15;
    const float* w = Wfc + (size_t)o * 1024;
    float acc = 0.f;
    #pragma unroll
    for (int qq = 0; qq < 32; ++qq) {
        acc += tile[s][qq]      * w[qq * 32 + s];
        acc += tile[s + 16][qq] * w[qq * 32 + s + 16];
    }
    part[o][s] = acc;
    __syncthreads();
    if (tid < 16) {
        float sum = bfc[tid];
        #pragma unroll
        for (int ss = 0; ss < 16; ++ss) sum += part[tid][ss];
        yws[i * 16 + tid] = sum;
    }
}

// K6b: layernorm(batch axis) + relu + log_softmax(batch axis) on y [32][16]
__global__ void __launch_bounds__(512) head_final_kernel(const float* __restrict__ yws,
        const float* __restrict__ gamma, const float* __restrict__ beta,
        float* __restrict__ out)
{
    __shared__ float ys[16][33];
    __shared__ float cstat[16];
    int tid = threadIdx.x;
    int i = tid >> 4, o = tid & 15;
    ys[o][i] = yws[tid];
    __syncthreads();
    if (tid < 16) {
        float mean = 0.f;
        for (int ii = 0; ii < 32; ++ii) mean += ys[tid][ii];
        mean *= (1.f / 32.f);
        float var = 0.f;
        for (int ii = 0; ii < 32; ++ii) { float d = ys[tid][ii] - mean; var += d * d; }
        var *= (1.f / 32.f);
        float inv = 1.f / sqrtf(var + 1e-5f);
        float g = gamma[tid], bt = beta[tid];
        float mx = -3.4e38f;
        for (int ii = 0; ii < 32; ++ii) {
            float v = g * (ys[tid][ii] - mean) * inv + bt;
            v = fmaxf(v, 0.f);
            ys[tid][ii] = v;
            mx = fmaxf(mx, v);
        }
        float s = 0.f;
        for (int ii = 0; ii < 32; ++ii) s += expf(ys[tid][ii] - mx);
        cstat[tid] = mx + logf(s);
    }
    __syncthreads();
    out[tid] = ys[o][i] - cstat[o];
}

extern "C" void kernel_launch(void* const* d_in, const int* in_sizes, int n_in,
                              void* d_out, int out_size, void* d_ws, size_t ws_size,
                              hipStream_t stream) {
    const int* x            = (const int*)d_in[0];
    const void* xm          = d_in[1];
    const float* x_feature  = (const float*)d_in[2];
    const int* lens         = (const int*)d_in[3];
    const float* emb    = (const float*)d_in[6];
    const float* w_attn = (const float*)d_in[7];
    const float* b_attn = (const float*)d_in[8];
    const float* Wih_f  = (const float*)d_in[9];
    const float* Whh_f  = (const float*)d_in[10];
    const float* bih_f  = (const float*)d_in[11];
    const float* bhh_f  = (const float*)d_in[12];
    const float* Wih_b  = (const float*)d_in[13];
    const float* bih_b  = (const float*)d_in[15];
    const float* bhh_b  = (const float*)d_in[16];
    const float* Wfc    = (const float*)d_in[17];
    const float* bfc    = (const float*)d_in[18];
    const float* gamma  = (const float*)d_in[19];
    const float* beta   = (const float*)d_in[20];

    float* ws    = (float*)d_ws;
    float* seq   = ws;                                    // 442368
    float* Ain   = seq + (size_t)PP_ * BB_ * DD_;         // 1572864
    float* hb    = Ain + (size_t)PP_ * BB_ * G4_;         // 16384
    float* hbuf  = hb + (size_t)BB_ * HH_;                // 16384
    float* cbuf  = hbuf + (size_t)BB_ * HH_;              // 16384
    float* AfA   = cbuf + (size_t)BB_ * HH_;              // 8192
    float* AfB   = AfA + 8192;                            // 8192
    float* Bfrag = AfB + 8192;                            // 524288 (1M bf16)
    float* Wbf   = Bfrag + 524288;                        // 589824 (1.18M bf16)
    float* yws   = Wbf + 589824;                          // 512
    int*  mflag  = (int*)(yws + 512);                     // 1  (~12.8 MB total)

    float* outp = (float*)d_out;

    detect_mask_kernel<<<dim3(1), dim3(256), 0, stream>>>(
        (const unsigned int*)xm, mflag);
    whh_frag_kernel<<<dim3(512), dim3(256), 0, stream>>>(
        Whh_f, (unsigned short*)Bfrag);
    cvt_bf16_kernel<<<dim3(1152), dim3(256), 0, stream>>>(
        Wih_f, (unsigned short*)Wbf, 294912);
    attn_rep_kernel<<<dim3(BB_ * PP_), dim3(256), 0, stream>>>(
        x, xm, mflag, x_feature, emb, w_attn, b_attn, seq);
    init2_kernel<<<dim3(64), dim3(256), 0, stream>>>(AfA, cbuf);
    in_gates_mfma_kernel<<<dim3(16, 48), dim3(256), 0, stream>>>(
        seq, (const unsigned short*)Wbf, bih_f, bhh_f, Ain);
    bwd_last2_kernel<<<dim3(64), dim3(256), 0, stream>>>(
        seq, lens, Wih_b, bih_b, bhh_b, hb);
    for (int t = 0; t < PP_; ++t) {
        const unsigned short* Asrc = (const unsigned short*)((t & 1) ? AfB : AfA);
        unsigned short* Adst       = (unsigned short*)((t & 1) ? AfA : AfB);
        lstm_mfma_kernel<<<dim3(64), dim3(256), 0, stream>>>(
            Asrc, Adst, cbuf, hbuf, Ain + (size_t)t * BB_ * G4_,
            (const unsigned short*)Bfrag);
    }
    fc_head_kernel<<<dim3(32), dim3(256), 0, stream>>>(
        hbuf, hb, lens, Wfc, bfc, yws);
    head_final_kernel<<<dim3(1), dim3(512), 0, stream>>>(
        yws, gamma, beta, outp);
}